// Round 1
// baseline (534.026 us; speedup 1.0000x reference)
//
#include <hip/hip_runtime.h>

#define BATCH 16
#define TXT   320
#define NMELC 80
#define MELT  2000
#define PADM  1.0e12f
#define EPSC  1e-7f

// ---------------------------------------------------------------------------
// Kernel A: log_prob[b,j,t] = s*(xx - 2xm + mm),  s = -0.5/80
// Decomposed as dot(G[j,:], F[t,:]) + bias[j] over K=160:
//   c <  80: G = s*inv_var,          F = x^2
//   c >= 80: G = -2*s*mu*inv_var,    F = x
// grid (16 t-tiles x128, 5 j-tiles x64, 16 b), 256 threads, 4j x 8t / thread
// ---------------------------------------------------------------------------
__global__ __launch_bounds__(256) void lp_kernel(
    const float* __restrict__ mlv,   // (B,320,160)
    const float* __restrict__ ms,    // (B,80,2000)
    float* __restrict__ out_lp,      // (B,320,2000)  (d_out+1)
    float* __restrict__ lpT,         // (B,2000,320) transposed scratch or null
    int has_lpT)
{
    __shared__ float Gt[16][64];
    __shared__ float Ft[16][128];
    __shared__ float bias_s[64];
    __shared__ float bias_p[256];

    const int b   = blockIdx.z;
    const int j0  = blockIdx.y * 64;
    const int t0  = blockIdx.x * 128;
    const int tid = threadIdx.x;
    const float s = -0.00625f;  // -0.5/80

    const float* mlv_b = mlv + (size_t)b * TXT * 160;
    const float* ms_b  = ms  + (size_t)b * NMELC * MELT;

    // --- cooperative bias pass: 4 threads per j, 20 c-terms each -----------
    {
        const int jj = tid >> 2;         // 0..63
        const int q  = tid & 3;          // 0..3
        const float* p = mlv_b + (size_t)(j0 + jj) * 160 + q * 20;
        float part = 0.f;
        #pragma unroll
        for (int c = 0; c < 20; ++c) {
            float mu = p[c];
            float lv = p[c + 80];
            float iv = __expf(-lv);
            part += mu * mu * iv + lv;
        }
        bias_p[tid] = part;
    }
    __syncthreads();
    if (tid < 64) {
        float v = bias_p[tid * 4] + bias_p[tid * 4 + 1] +
                  bias_p[tid * 4 + 2] + bias_p[tid * 4 + 3];
        bias_s[tid] = s * v;
    }

    float acc[4][8];
    #pragma unroll
    for (int i = 0; i < 4; ++i)
        #pragma unroll
        for (int k = 0; k < 8; ++k) acc[i][k] = 0.f;

    const int jg = tid >> 4;   // 0..15 -> j = j0 + jg*4 + ji
    const int tg = tid & 15;   // 0..15 -> t = t0 + tg*8 + ti

    for (int kc = 0; kc < 10; ++kc) {
        const int c0 = kc * 8;
        __syncthreads();
        // stage G (computed inline from mu/logvar; mlv tile is L1-hot)
        #pragma unroll
        for (int i = 0; i < 2; ++i) {
            int f   = tid + i * 256;
            int cr  = f >> 6;            // 0..7
            int col = f & 63;
            float mu = mlv_b[(size_t)(j0 + col) * 160 + (c0 + cr)];
            float lv = mlv_b[(size_t)(j0 + col) * 160 + (80 + c0 + cr)];
            float iv = __expf(-lv);
            Gt[cr][col]     = s * iv;
            Gt[cr + 8][col] = -2.f * s * mu * iv;
        }
        // stage F from melspec (coalesced along t)
        #pragma unroll
        for (int i = 0; i < 4; ++i) {
            int f   = tid + i * 256;
            int row = f >> 7;            // 0..7
            int col = f & 127;
            int t   = t0 + col;
            float v = (t < MELT) ? ms_b[(size_t)(c0 + row) * MELT + t] : 0.f;
            Ft[row][col]     = v * v;
            Ft[row + 8][col] = v;
        }
        __syncthreads();
        #pragma unroll
        for (int k = 0; k < 16; ++k) {
            float4 g  = *(const float4*)&Gt[k][jg * 4];
            float4 f0 = *(const float4*)&Ft[k][tg * 8];
            float4 f1 = *(const float4*)&Ft[k][tg * 8 + 4];
            float ga[4] = {g.x, g.y, g.z, g.w};
            float fa[8] = {f0.x, f0.y, f0.z, f0.w, f1.x, f1.y, f1.z, f1.w};
            #pragma unroll
            for (int ji = 0; ji < 4; ++ji)
                #pragma unroll
                for (int ti = 0; ti < 8; ++ti)
                    acc[ji][ti] = fmaf(ga[ji], fa[ti], acc[ji][ti]);
        }
    }

    // --- epilogue ----------------------------------------------------------
    #pragma unroll
    for (int ji = 0; ji < 4; ++ji) {
        int j = j0 + jg * 4 + ji;
        float bs = bias_s[jg * 4 + ji];
        float* orow = out_lp + (size_t)(b * TXT + j) * MELT;
        #pragma unroll
        for (int ti = 0; ti < 8; ++ti) {
            int t = t0 + tg * 8 + ti;
            if (t < MELT) orow[t] = acc[ji][ti] + bs;   // d_out+1 is unaligned -> scalar stores
        }
    }
    if (has_lpT) {
        float bs0 = bias_s[jg * 4 + 0], bs1 = bias_s[jg * 4 + 1];
        float bs2 = bias_s[jg * 4 + 2], bs3 = bias_s[jg * 4 + 3];
        #pragma unroll
        for (int ti = 0; ti < 8; ++ti) {
            int t = t0 + tg * 8 + ti;
            if (t < MELT) {
                float4 v = make_float4(acc[0][ti] + bs0, acc[1][ti] + bs1,
                                       acc[2][ti] + bs2, acc[3][ti] + bs3);
                *(float4*)&lpT[((size_t)b * MELT + t) * TXT + (j0 + jg * 4)] = v;
            }
        }
    }
}

// ---------------------------------------------------------------------------
// Kernel B: forward DP. One block per batch, 320 threads (5 waves), alpha in
// registers, alpha[j-1] via LDS with parity double-buffer -> 1 barrier/step.
// alpha_new[j] = lse(alpha[j], alpha[j-1]) + EPS + lp[j,t];  alpha[-1] = -PAD
// ---------------------------------------------------------------------------
__global__ __launch_bounds__(320) void dp_kernel(
    const float* __restrict__ lp,    // (B,320,2000)
    const float* __restrict__ lpT,   // (B,2000,320) or null
    const int* __restrict__ tlen,
    const int* __restrict__ mlen,
    float* __restrict__ res,         // per-b alpha_last/ml (ws), or null
    float* __restrict__ out0,        // d_out[0] for atomic fallback
    int use_T)
{
    __shared__ float abuf[2][TXT + 1];
    const int b  = blockIdx.x;
    const int j  = threadIdx.x;
    const int tl = tlen[b];
    const int ml = mlen[b];

    if (j == 0) { abuf[0][0] = -PADM; abuf[1][0] = -PADM; }

    const float* lpp;
    size_t stride;
    if (use_T) { lpp = lpT + (size_t)b * MELT * TXT + j; stride = TXT; }
    else       { lpp = lp  + (size_t)(b * TXT + j) * MELT; stride = 1; }

    // t = 0 init: alpha[0] = lp[b,0,0], else -PAD
    float alpha = (j == 0) ? lp[(size_t)b * TXT * MELT] : -PADM;
    float lpn = lpp[stride];                 // prefetch t=1
    __syncthreads();

    const int tend = ml - 1;
    for (int t = 1; t <= tend; ++t) {
        float lpv = lpn;
        if (t < MELT - 1) lpn = lpp[(size_t)(t + 1) * stride];  // prefetch next
        int p = t & 1;
        abuf[p][j + 1] = alpha;
        __syncthreads();
        float prev = abuf[p][j];
        float m  = fmaxf(alpha, prev);
        float mn = fminf(alpha, prev);
        float e  = exp2f((mn - m) * 1.44269504f);
        float l  = log2f(1.0f + e) * 0.69314718f;
        alpha = m + l + (EPSC + lpv);
    }
    if (j == tl - 1) {
        float v = alpha / (float)ml;
        if (res) res[b] = v;
        else     atomicAdd(out0, -v / (float)BATCH);
    }
}

__global__ void zero1_kernel(float* out0) { out0[0] = 0.f; }

__global__ void fin_kernel(const float* __restrict__ res, float* __restrict__ out0)
{
    int l = threadIdx.x;
    float v = (l < BATCH) ? res[l] : 0.f;
    #pragma unroll
    for (int off = 32; off; off >>= 1) v += __shfl_down(v, off);
    if (l == 0) out0[0] = -(v / (float)BATCH);
}

// ---------------------------------------------------------------------------
extern "C" void kernel_launch(void* const* d_in, const int* in_sizes, int n_in,
                              void* d_out, int out_size, void* d_ws, size_t ws_size,
                              hipStream_t stream)
{
    const float* mlv = (const float*)d_in[0];
    const float* ms  = (const float*)d_in[1];
    const int*   tl  = (const int*)d_in[2];
    const int*   ml  = (const int*)d_in[3];
    float* out    = (float*)d_out;
    float* out_lp = out + 1;

    const size_t lpT_bytes = (size_t)BATCH * MELT * TXT * sizeof(float);
    bool res_ok  = ws_size >= 64;
    bool has_lpT = ws_size >= 64 + lpT_bytes;
    float* res = res_ok  ? (float*)d_ws : nullptr;
    float* lpT = has_lpT ? (float*)((char*)d_ws + 64) : nullptr;

    dim3 gA(16, 5, 16);   // t-tiles, j-tiles, batch
    lp_kernel<<<gA, 256, 0, stream>>>(mlv, ms, out_lp, lpT, has_lpT ? 1 : 0);

    if (!res_ok) zero1_kernel<<<1, 1, 0, stream>>>(out);
    dp_kernel<<<BATCH, TXT, 0, stream>>>(out_lp, lpT, tl, ml, res, out,
                                         has_lpT ? 1 : 0);
    if (res_ok) fin_kernel<<<1, 64, 0, stream>>>(res, out);
}

// Round 2
// 377.427 us; speedup vs baseline: 1.4149x; 1.4149x over previous
//
#include <hip/hip_runtime.h>

#define BATCH 16
#define TXT   320
#define NMELC 80
#define MELT  2000
#define PADM  1.0e12f
#define EPSC  1e-7f

// ---------------------------------------------------------------------------
// Kernel A: log_prob[b,j,t] = s*(xx - 2xm + mm),  s = -0.5/80
// Decomposed as dot(G[j,:], F[t,:]) + bias[j] over K=160:
//   c <  80: G = s*inv_var,          F = x^2
//   c >= 80: G = -2*s*mu*inv_var,    F = x
// grid (16 t-tiles x128, 5 j-tiles x64, 16 b), 256 threads, 4j x 8t / thread
// lpT (B, MELT, TXT) gets lp + EPSC folded in (for the DP kernel).
// ---------------------------------------------------------------------------
__global__ __launch_bounds__(256) void lp_kernel(
    const float* __restrict__ mlv,   // (B,320,160)
    const float* __restrict__ ms,    // (B,80,2000)
    float* __restrict__ out_lp,      // (B,320,2000)  (d_out+1)
    float* __restrict__ lpT,         // (B,2000,320) transposed scratch or null
    int has_lpT)
{
    __shared__ float Gt[16][64];
    __shared__ float Ft[16][128];
    __shared__ float bias_s[64];
    __shared__ float bias_p[256];

    const int b   = blockIdx.z;
    const int j0  = blockIdx.y * 64;
    const int t0  = blockIdx.x * 128;
    const int tid = threadIdx.x;
    const float s = -0.00625f;  // -0.5/80

    const float* mlv_b = mlv + (size_t)b * TXT * 160;
    const float* ms_b  = ms  + (size_t)b * NMELC * MELT;

    // --- cooperative bias pass: 4 threads per j, 20 c-terms each -----------
    {
        const int jj = tid >> 2;         // 0..63
        const int q  = tid & 3;          // 0..3
        const float* p = mlv_b + (size_t)(j0 + jj) * 160 + q * 20;
        float part = 0.f;
        #pragma unroll
        for (int c = 0; c < 20; ++c) {
            float mu = p[c];
            float lv = p[c + 80];
            float iv = __expf(-lv);
            part += mu * mu * iv + lv;
        }
        bias_p[tid] = part;
    }
    __syncthreads();
    if (tid < 64) {
        float v = bias_p[tid * 4] + bias_p[tid * 4 + 1] +
                  bias_p[tid * 4 + 2] + bias_p[tid * 4 + 3];
        bias_s[tid] = s * v;
    }

    float acc[4][8];
    #pragma unroll
    for (int i = 0; i < 4; ++i)
        #pragma unroll
        for (int k = 0; k < 8; ++k) acc[i][k] = 0.f;

    const int jg = tid >> 4;   // 0..15 -> j = j0 + jg*4 + ji
    const int tg = tid & 15;   // 0..15 -> t = t0 + tg*8 + ti

    for (int kc = 0; kc < 10; ++kc) {
        const int c0 = kc * 8;
        __syncthreads();
        // stage G (computed inline from mu/logvar; mlv tile is L1-hot)
        #pragma unroll
        for (int i = 0; i < 2; ++i) {
            int f   = tid + i * 256;
            int cr  = f >> 6;            // 0..7
            int col = f & 63;
            float mu = mlv_b[(size_t)(j0 + col) * 160 + (c0 + cr)];
            float lv = mlv_b[(size_t)(j0 + col) * 160 + (80 + c0 + cr)];
            float iv = __expf(-lv);
            Gt[cr][col]     = s * iv;
            Gt[cr + 8][col] = -2.f * s * mu * iv;
        }
        // stage F from melspec (coalesced along t)
        #pragma unroll
        for (int i = 0; i < 4; ++i) {
            int f   = tid + i * 256;
            int row = f >> 7;            // 0..7
            int col = f & 127;
            int t   = t0 + col;
            float v = (t < MELT) ? ms_b[(size_t)(c0 + row) * MELT + t] : 0.f;
            Ft[row][col]     = v * v;
            Ft[row + 8][col] = v;
        }
        __syncthreads();
        #pragma unroll
        for (int k = 0; k < 16; ++k) {
            float4 g  = *(const float4*)&Gt[k][jg * 4];
            float4 f0 = *(const float4*)&Ft[k][tg * 8];
            float4 f1 = *(const float4*)&Ft[k][tg * 8 + 4];
            float ga[4] = {g.x, g.y, g.z, g.w};
            float fa[8] = {f0.x, f0.y, f0.z, f0.w, f1.x, f1.y, f1.z, f1.w};
            #pragma unroll
            for (int ji = 0; ji < 4; ++ji)
                #pragma unroll
                for (int ti = 0; ti < 8; ++ti)
                    acc[ji][ti] = fmaf(ga[ji], fa[ti], acc[ji][ti]);
        }
    }

    // --- epilogue ----------------------------------------------------------
    #pragma unroll
    for (int ji = 0; ji < 4; ++ji) {
        int j = j0 + jg * 4 + ji;
        float bs = bias_s[jg * 4 + ji];
        float* orow = out_lp + (size_t)(b * TXT + j) * MELT;
        #pragma unroll
        for (int ti = 0; ti < 8; ++ti) {
            int t = t0 + tg * 8 + ti;
            if (t < MELT) orow[t] = acc[ji][ti] + bs;   // d_out+1 is unaligned -> scalar stores
        }
    }
    if (has_lpT) {
        // fold +EPSC into the DP copy (compensated at DP init)
        float bs0 = bias_s[jg * 4 + 0] + EPSC, bs1 = bias_s[jg * 4 + 1] + EPSC;
        float bs2 = bias_s[jg * 4 + 2] + EPSC, bs3 = bias_s[jg * 4 + 3] + EPSC;
        #pragma unroll
        for (int ti = 0; ti < 8; ++ti) {
            int t = t0 + tg * 8 + ti;
            if (t < MELT) {
                float4 v = make_float4(acc[0][ti] + bs0, acc[1][ti] + bs1,
                                       acc[2][ti] + bs2, acc[3][ti] + bs3);
                *(float4*)&lpT[((size_t)b * MELT + t) * TXT + (j0 + jg * 4)] = v;
            }
        }
    }
}

// ---------------------------------------------------------------------------
// Kernel B: forward DP, single wave per batch. Lane owns 5 consecutive j in
// registers; neighbor alpha[j-1] at the chunk boundary via one __shfl_up of
// the freshly-computed a4 per step. No LDS, no barriers. lp loads prefetched
// 8 steps ahead (two 4-step register groups).
// ---------------------------------------------------------------------------
__device__ __forceinline__ float lse2(float x, float y) {
    float m  = fmaxf(x, y);
    float mn = fminf(x, y);
    float e  = __builtin_amdgcn_exp2f((mn - m) * 1.44269504f);
    float l  = __builtin_amdgcn_logf(1.0f + e) * 0.69314718f;  // v_log = log2
    return m + l;
}

__global__ __launch_bounds__(64) void dp_kernel(
    const float* __restrict__ lpE,   // lp with +EPSC folded; layout per strides
    const int* __restrict__ tlen,
    const int* __restrict__ mlen,
    float* __restrict__ res,         // per-b alpha_last/ml (ws), or null
    float* __restrict__ out0,        // d_out[0] for atomic fallback
    int ts, int js)                  // strides: addr = b*... + t*ts + j*js
{
    const int b    = blockIdx.x;
    const int lane = threadIdx.x;
    const int tl   = tlen[b];
    const int ml   = mlen[b];

    const float* base = lpE + (size_t)b * MELT * TXT + (size_t)(lane * 5) * js;
    const float* b0 = base;
    const float* b1 = base + js;
    const float* b2 = base + 2 * js;
    const float* b3 = base + 3 * js;
    const float* b4 = base + 4 * js;

    float a0 = -PADM, a1 = -PADM, a2 = -PADM, a3 = -PADM, a4 = -PADM;
    float pt = -PADM;                       // alpha_{t-1}[lane*5 - 1]
    if (lane == 0) a0 = b0[0] - EPSC;       // t=0 init: alpha[0]=lp[b,0,0]

    const int tend = ml - 1;

    auto step = [&](float l0, float l1, float l2, float l3, float l4) {
        float n4 = lse2(a3, a4) + l4;       // compute boundary value first
        float sh = __shfl_up(n4, 1);        // issue shuffle early
        float n3 = lse2(a2, a3) + l3;
        float n2 = lse2(a1, a2) + l2;
        float n1 = lse2(a0, a1) + l1;
        float n0 = lse2(pt, a0) + l0;
        a0 = n0; a1 = n1; a2 = n2; a3 = n3; a4 = n4;
        pt = (lane == 0) ? -PADM : sh;
    };

    float X[4][5], Y[4][5];
    #define LOADG(BUF, T0)                                                   \
    {                                                                        \
        _Pragma("unroll")                                                    \
        for (int q = 0; q < 4; ++q) {                                        \
            int tc = (T0) + q; if (tc > MELT - 1) tc = MELT - 1;             \
            size_t o = (size_t)tc * ts;                                      \
            BUF[q][0] = b0[o]; BUF[q][1] = b1[o]; BUF[q][2] = b2[o];         \
            BUF[q][3] = b3[o]; BUF[q][4] = b4[o];                            \
        }                                                                    \
    }
    #define STEP4(BUF)                                                       \
    {                                                                        \
        _Pragma("unroll")                                                    \
        for (int q = 0; q < 4; ++q)                                          \
            step(BUF[q][0], BUF[q][1], BUF[q][2], BUF[q][3], BUF[q][4]);     \
    }

    int t = 1;
    LOADG(X, t);
    while (t + 7 <= tend) {
        LOADG(Y, t + 4);
        STEP4(X);
        LOADG(X, t + 8);
        STEP4(Y);
        t += 8;
    }
    // tail (<= 7 steps): group X holds lp for t..t+3 already
    {
        int q = 0;
        while (t <= tend && q < 4) {
            step(X[q][0], X[q][1], X[q][2], X[q][3], X[q][4]);
            ++t; ++q;
        }
        while (t <= tend) {
            size_t o = (size_t)t * ts;
            step(b0[o], b1[o], b2[o], b3[o], b4[o]);
            ++t;
        }
    }
    #undef LOADG
    #undef STEP4

    const int jlast = tl - 1;
    if (lane == jlast / 5) {
        int ji = jlast % 5;
        float v = a0;
        v = (ji == 1) ? a1 : v;
        v = (ji == 2) ? a2 : v;
        v = (ji == 3) ? a3 : v;
        v = (ji == 4) ? a4 : v;
        v = v / (float)ml;
        if (res) res[b] = v;
        else     atomicAdd(out0, -v / (float)BATCH);
    }
}

__global__ void zero1_kernel(float* out0) { out0[0] = 0.f; }

__global__ void fin_kernel(const float* __restrict__ res, float* __restrict__ out0)
{
    int l = threadIdx.x;
    float v = (l < BATCH) ? res[l] : 0.f;
    #pragma unroll
    for (int off = 32; off; off >>= 1) v += __shfl_down(v, off);
    if (l == 0) out0[0] = -(v / (float)BATCH);
}

// ---------------------------------------------------------------------------
extern "C" void kernel_launch(void* const* d_in, const int* in_sizes, int n_in,
                              void* d_out, int out_size, void* d_ws, size_t ws_size,
                              hipStream_t stream)
{
    const float* mlv = (const float*)d_in[0];
    const float* ms  = (const float*)d_in[1];
    const int*   tl  = (const int*)d_in[2];
    const int*   ml  = (const int*)d_in[3];
    float* out    = (float*)d_out;
    float* out_lp = out + 1;

    const size_t lpT_bytes = (size_t)BATCH * MELT * TXT * sizeof(float);
    bool res_ok  = ws_size >= 64;
    bool has_lpT = ws_size >= 64 + lpT_bytes;
    float* res = res_ok  ? (float*)d_ws : nullptr;
    float* lpT = has_lpT ? (float*)((char*)d_ws + 64) : nullptr;

    dim3 gA(16, 5, 16);   // t-tiles, j-tiles, batch
    lp_kernel<<<gA, 256, 0, stream>>>(mlv, ms, out_lp, lpT, has_lpT ? 1 : 0);

    if (!res_ok) zero1_kernel<<<1, 1, 0, stream>>>(out);
    if (has_lpT) {
        // lpT layout (B, MELT, TXT): t-stride TXT, j-stride 1; EPS folded in
        dp_kernel<<<BATCH, 64, 0, stream>>>(lpT, tl, ml, res, out, TXT, 1);
    } else {
        // fall back to reading out_lp (B, TXT, MELT): t-stride 1, j-stride MELT
        // (no EPS folded -> tiny 1e-7/step deficit, well under threshold)
        dp_kernel<<<BATCH, 64, 0, stream>>>(out_lp, tl, ml, res, out, 1, MELT);
    }
    if (res_ok) fin_kernel<<<1, 64, 0, stream>>>(res, out);
}

// Round 3
// 344.516 us; speedup vs baseline: 1.5501x; 1.0955x over previous
//
#include <hip/hip_runtime.h>

#define BATCH 16
#define TXT   320
#define NMELC 80
#define MELT  2000
#define PADM  1.0e12f
#define EPSC  1e-7f
#define L2E   1.4426950408889634f
#define LN2   0.6931471805599453f

// ---------------------------------------------------------------------------
// Kernel A: log_prob[b,j,t] = s*(xx - 2xm + mm),  s = -0.5/80
//   c <  80: G = s*inv_var,          F = x^2
//   c >= 80: G = -2*s*mu*inv_var,    F = x
// tile 64j x 256t, 256 threads, 8j x 8t per thread
// ---------------------------------------------------------------------------
__global__ __launch_bounds__(256) void lp_kernel(
    const float* __restrict__ mlv,   // (B,320,160)
    const float* __restrict__ ms,    // (B,80,2000)
    float* __restrict__ out_lp)      // (B,320,2000)  (d_out+1)
{
    __shared__ float Gt[16][64];
    __shared__ float Ft[16][256];
    __shared__ float bias_s[64];
    __shared__ float bias_p[256];

    const int b   = blockIdx.z;
    const int j0  = blockIdx.y * 64;
    const int t0  = blockIdx.x * 256;
    const int tid = threadIdx.x;
    const float s = -0.00625f;  // -0.5/80

    const float* mlv_b = mlv + (size_t)b * TXT * 160;
    const float* ms_b  = ms  + (size_t)b * NMELC * MELT;

    // --- cooperative bias pass: 4 threads per j, 20 c-terms each -----------
    {
        const int jj = tid >> 2;
        const int q  = tid & 3;
        const float* p = mlv_b + (size_t)(j0 + jj) * 160 + q * 20;
        float part = 0.f;
        #pragma unroll
        for (int c = 0; c < 20; ++c) {
            float mu = p[c];
            float lv = p[c + 80];
            float iv = __expf(-lv);
            part += mu * mu * iv + lv;
        }
        bias_p[tid] = part;
    }
    __syncthreads();
    if (tid < 64) {
        float v = bias_p[tid * 4] + bias_p[tid * 4 + 1] +
                  bias_p[tid * 4 + 2] + bias_p[tid * 4 + 3];
        bias_s[tid] = s * v;
    }

    float acc[8][8];
    #pragma unroll
    for (int i = 0; i < 8; ++i)
        #pragma unroll
        for (int k = 0; k < 8; ++k) acc[i][k] = 0.f;

    const int jg = tid >> 5;   // 0..7  -> j = j0 + jg*8 + ji
    const int tg = tid & 31;   // 0..31 -> t = t0 + tg*8 + ti

    for (int kc = 0; kc < 10; ++kc) {
        const int c0 = kc * 8;
        __syncthreads();
        // stage G (inline exp from mu/logvar; mlv tile is cache-hot)
        #pragma unroll
        for (int i = 0; i < 2; ++i) {
            int f   = tid + i * 256;
            int cr  = f >> 6;            // 0..7
            int col = f & 63;
            float mu = mlv_b[(size_t)(j0 + col) * 160 + (c0 + cr)];
            float lv = mlv_b[(size_t)(j0 + col) * 160 + (80 + c0 + cr)];
            float iv = __expf(-lv);
            Gt[cr][col]     = s * iv;
            Gt[cr + 8][col] = -2.f * s * mu * iv;
        }
        // stage F from melspec, float4 along t (rows are 16B-aligned: 2000*4B)
        #pragma unroll
        for (int i = 0; i < 2; ++i) {
            int f   = tid + i * 256;
            int row = f >> 6;            // 0..7
            int c4  = f & 63;            // float4 index within 256-t tile
            int t   = t0 + c4 * 4;
            float4 v = (t + 3 < MELT)
                ? *(const float4*)&ms_b[(size_t)(c0 + row) * MELT + t]
                : make_float4(0.f, 0.f, 0.f, 0.f);
            *(float4*)&Ft[row][c4 * 4] =
                make_float4(v.x * v.x, v.y * v.y, v.z * v.z, v.w * v.w);
            *(float4*)&Ft[row + 8][c4 * 4] = v;
        }
        __syncthreads();
        #pragma unroll
        for (int k = 0; k < 16; ++k) {
            float4 g0 = *(const float4*)&Gt[k][jg * 8];
            float4 g1 = *(const float4*)&Gt[k][jg * 8 + 4];
            float4 f0 = *(const float4*)&Ft[k][tg * 8];
            float4 f1 = *(const float4*)&Ft[k][tg * 8 + 4];
            float ga[8] = {g0.x, g0.y, g0.z, g0.w, g1.x, g1.y, g1.z, g1.w};
            float fa[8] = {f0.x, f0.y, f0.z, f0.w, f1.x, f1.y, f1.z, f1.w};
            #pragma unroll
            for (int ji = 0; ji < 8; ++ji)
                #pragma unroll
                for (int ti = 0; ti < 8; ++ti)
                    acc[ji][ti] = fmaf(ga[ji], fa[ti], acc[ji][ti]);
        }
    }

    // --- epilogue (d_out+1 is 4-mod-16 aligned -> scalar stores) -----------
    #pragma unroll
    for (int ji = 0; ji < 8; ++ji) {
        int j = j0 + jg * 8 + ji;
        float bs = bias_s[jg * 8 + ji];
        float* orow = out_lp + (size_t)(b * TXT + j) * MELT;
        #pragma unroll
        for (int ti = 0; ti < 8; ++ti) {
            int t = t0 + tg * 8 + ti;
            if (t < MELT) orow[t] = acc[ji][ti] + bs;
        }
    }
}

// ---------------------------------------------------------------------------
// Kernel B: forward DP, 5 waves/batch, 1 j per lane, skewed systolic time:
// lane l computes step t at iteration i = t + l. Neighbor alpha arrives via a
// 2-deep shfl_up pipeline (latency off critical path). Cross-wave boundary
// through an LDS ring (bnd[w][t], full length - no wrap) + prog[] counters,
// polled once per 8-iteration group. Log2-domain alpha. No barriers in loop.
// ---------------------------------------------------------------------------
__global__ __launch_bounds__(320) void dp_kernel(
    const float* __restrict__ lp,    // (B,320,2000) = out_lp
    const int* __restrict__ tlen,
    const int* __restrict__ mlen,
    float* __restrict__ res,         // per-b result (ws), or null
    float* __restrict__ out0)        // d_out[0] fallback
{
    __shared__ float bnd[4][2056];
    __shared__ int   prog[4];

    const int b    = blockIdx.x;
    const int tid  = threadIdx.x;
    const int w    = tid >> 6;
    const int l    = tid & 63;
    const int j    = tid;
    const int tend = mlen[b] - 1;
    const int tl   = tlen[b];

    if (tid < 4) prog[tid] = 0;

    const float* lprow = lp + (size_t)(b * TXT + j) * MELT;
    float first = lp[(size_t)b * TXT * MELT];
    float A    = (j == 0) ? first * L2E : -PADM;
    float Afin = A;

    if (l == 63 && w < 4) bnd[w][0] = -PADM;
    __syncthreads();

    // prime the 2-deep shuffle pipe with alpha_0
    float ptA = __shfl_up(A, 1);
    float ptB = ptA;
    const bool is0     = (l == 0);
    const bool isPub   = (l == 63) && (w < 4);
    const bool hasRing = (w > 0);

    // prefetch lp for iterations 1..8 (scaled into log2 domain, EPS folded)
    float Pc[8], Pn[8];
    #pragma unroll
    for (int q = 0; q < 8; ++q) {
        int t = 1 + q - l;
        t = t < 0 ? 0 : (t > tend ? tend : t);
        Pc[q] = fmaf(lprow[t], L2E, EPSC * L2E);
    }

    const int imax = tend + 63;
    for (int i0 = 1; i0 <= imax; i0 += 8) {
        // --- ring values for this group (lane0's left inputs) --------------
        float bq[8];
        if (hasRing) {
            int t0 = i0 - 1;                       // multiple of 8
            int need = t0 + 7; if (need > tend - 1) need = tend - 1;
            if (need >= 1) {
                volatile int* pv = &prog[w - 1];
                while (*pv < need) __builtin_amdgcn_s_sleep(2);
            }
            int rb = t0 > 2048 ? 2048 : t0;        // stay in-bounds
            float4 r0 = *(const float4*)&bnd[w - 1][rb];
            float4 r1 = *(const float4*)&bnd[w - 1][rb + 4];
            bq[0] = r0.x; bq[1] = r0.y; bq[2] = r0.z; bq[3] = r0.w;
            bq[4] = r1.x; bq[5] = r1.y; bq[6] = r1.z; bq[7] = r1.w;
        } else {
            #pragma unroll
            for (int q = 0; q < 8; ++q) bq[q] = -PADM;
        }
        // --- prefetch next group's lp --------------------------------------
        #pragma unroll
        for (int q = 0; q < 8; ++q) {
            int t = i0 + 8 + q - l;
            t = t < 0 ? 0 : (t > tend ? tend : t);
            Pn[q] = lprow[t];
        }
        // --- 8 systolic steps ----------------------------------------------
        float aq[8];
        const int vt = i0 - l;   // t at q=0 for this lane
        #pragma unroll
        for (int q = 0; q < 8; ++q) {
            float pt = is0 ? bq[q] : ptA;
            float m  = fmaxf(A, pt);
            float d  = A - pt;
            float e  = __builtin_amdgcn_exp2f(-fabsf(d));   // -abs is a free mod
            float lg = __builtin_amdgcn_logf(1.0f + e);     // v_log = log2
            float An = (m + lg) + Pc[q];
            int tq = vt + q;
            A = (tq >= 1) ? An : A;          // hold init until lane starts
            aq[q] = A;
            Afin = (tq == tend) ? A : Afin;  // latch final step
            float ns = __shfl_up(A, 1);
            ptA = ptB; ptB = ns;
        }
        // --- publish boundary (lane 63 of waves 0..3) ----------------------
        if (isPub) {
            int t63 = i0 - 63;
            #pragma unroll
            for (int q = 0; q < 8; ++q) {
                int tq = t63 + q;
                if (tq >= 1 && tq <= tend) bnd[w][tq] = aq[q];
            }
            __asm__ volatile("s_waitcnt lgkmcnt(0)" ::: "memory");
            int pgv = t63 + 7; if (pgv > tend) pgv = tend;
            if (pgv >= 1) prog[w] = pgv;
        }
        // --- rotate prefetch (scale into log2 domain) ----------------------
        #pragma unroll
        for (int q = 0; q < 8; ++q) Pc[q] = fmaf(Pn[q], L2E, EPSC * L2E);
    }

    if (j == tl - 1) {
        float v = Afin * LN2 / (float)(tend + 1);
        if (res) res[b] = v;
        else     atomicAdd(out0, -v / (float)BATCH);
    }
}

__global__ void zero1_kernel(float* out0) { out0[0] = 0.f; }

__global__ void fin_kernel(const float* __restrict__ res, float* __restrict__ out0)
{
    int l = threadIdx.x;
    float v = (l < BATCH) ? res[l] : 0.f;
    #pragma unroll
    for (int off = 32; off; off >>= 1) v += __shfl_down(v, off);
    if (l == 0) out0[0] = -(v / (float)BATCH);
}

// ---------------------------------------------------------------------------
extern "C" void kernel_launch(void* const* d_in, const int* in_sizes, int n_in,
                              void* d_out, int out_size, void* d_ws, size_t ws_size,
                              hipStream_t stream)
{
    const float* mlv = (const float*)d_in[0];
    const float* ms  = (const float*)d_in[1];
    const int*   tl  = (const int*)d_in[2];
    const int*   ml  = (const int*)d_in[3];
    float* out    = (float*)d_out;
    float* out_lp = out + 1;

    bool res_ok = ws_size >= 64;
    float* res = res_ok ? (float*)d_ws : nullptr;

    dim3 gA(8, 5, 16);   // t-tiles(256), j-tiles(64), batch
    lp_kernel<<<gA, 256, 0, stream>>>(mlv, ms, out_lp);

    if (!res_ok) zero1_kernel<<<1, 1, 0, stream>>>(out);
    dp_kernel<<<BATCH, 320, 0, stream>>>(out_lp, tl, ml, res, out);
    if (res_ok) fin_kernel<<<1, 64, 0, stream>>>(res, out);
}

// Round 4
// 255.155 us; speedup vs baseline: 2.0929x; 1.3502x over previous
//
#include <hip/hip_runtime.h>

#define BATCH 16
#define TXT   320
#define NMELC 80
#define MELT  2000
#define PADM  1.0e12f
#define EPSC  1e-7f
#define L2E   1.4426950408889634f
#define LN2   0.6931471805599453f
#define EPSL2 1.4426950e-7f

// ---------------------------------------------------------------------------
// Kernel A: log_prob[b,j,t] = s*(xx - 2xm + mm),  s = -0.5/80
//   c <  80: G = s*inv_var,          F = x^2
//   c >= 80: G = -2*s*mu*inv_var,    F = x
// tile 64j x 256t, 256 threads, 8j x 8t per thread  (unchanged from round 3)
// ---------------------------------------------------------------------------
__global__ __launch_bounds__(256) void lp_kernel(
    const float* __restrict__ mlv,   // (B,320,160)
    const float* __restrict__ ms,    // (B,80,2000)
    float* __restrict__ out_lp)      // (B,320,2000)  (d_out+1)
{
    __shared__ float Gt[16][64];
    __shared__ float Ft[16][256];
    __shared__ float bias_s[64];
    __shared__ float bias_p[256];

    const int b   = blockIdx.z;
    const int j0  = blockIdx.y * 64;
    const int t0  = blockIdx.x * 256;
    const int tid = threadIdx.x;
    const float s = -0.00625f;  // -0.5/80

    const float* mlv_b = mlv + (size_t)b * TXT * 160;
    const float* ms_b  = ms  + (size_t)b * NMELC * MELT;

    {
        const int jj = tid >> 2;
        const int q  = tid & 3;
        const float* p = mlv_b + (size_t)(j0 + jj) * 160 + q * 20;
        float part = 0.f;
        #pragma unroll
        for (int c = 0; c < 20; ++c) {
            float mu = p[c];
            float lv = p[c + 80];
            float iv = __expf(-lv);
            part += mu * mu * iv + lv;
        }
        bias_p[tid] = part;
    }
    __syncthreads();
    if (tid < 64) {
        float v = bias_p[tid * 4] + bias_p[tid * 4 + 1] +
                  bias_p[tid * 4 + 2] + bias_p[tid * 4 + 3];
        bias_s[tid] = s * v;
    }

    float acc[8][8];
    #pragma unroll
    for (int i = 0; i < 8; ++i)
        #pragma unroll
        for (int k = 0; k < 8; ++k) acc[i][k] = 0.f;

    const int jg = tid >> 5;   // 0..7
    const int tg = tid & 31;   // 0..31

    for (int kc = 0; kc < 10; ++kc) {
        const int c0 = kc * 8;
        __syncthreads();
        #pragma unroll
        for (int i = 0; i < 2; ++i) {
            int f   = tid + i * 256;
            int cr  = f >> 6;
            int col = f & 63;
            float mu = mlv_b[(size_t)(j0 + col) * 160 + (c0 + cr)];
            float lv = mlv_b[(size_t)(j0 + col) * 160 + (80 + c0 + cr)];
            float iv = __expf(-lv);
            Gt[cr][col]     = s * iv;
            Gt[cr + 8][col] = -2.f * s * mu * iv;
        }
        #pragma unroll
        for (int i = 0; i < 2; ++i) {
            int f   = tid + i * 256;
            int row = f >> 6;
            int c4  = f & 63;
            int t   = t0 + c4 * 4;
            float4 v = (t + 3 < MELT)
                ? *(const float4*)&ms_b[(size_t)(c0 + row) * MELT + t]
                : make_float4(0.f, 0.f, 0.f, 0.f);
            *(float4*)&Ft[row][c4 * 4] =
                make_float4(v.x * v.x, v.y * v.y, v.z * v.z, v.w * v.w);
            *(float4*)&Ft[row + 8][c4 * 4] = v;
        }
        __syncthreads();
        #pragma unroll
        for (int k = 0; k < 16; ++k) {
            float4 g0 = *(const float4*)&Gt[k][jg * 8];
            float4 g1 = *(const float4*)&Gt[k][jg * 8 + 4];
            float4 f0 = *(const float4*)&Ft[k][tg * 8];
            float4 f1 = *(const float4*)&Ft[k][tg * 8 + 4];
            float ga[8] = {g0.x, g0.y, g0.z, g0.w, g1.x, g1.y, g1.z, g1.w};
            float fa[8] = {f0.x, f0.y, f0.z, f0.w, f1.x, f1.y, f1.z, f1.w};
            #pragma unroll
            for (int ji = 0; ji < 8; ++ji)
                #pragma unroll
                for (int ti = 0; ti < 8; ++ti)
                    acc[ji][ti] = fmaf(ga[ji], fa[ti], acc[ji][ti]);
        }
    }

    #pragma unroll
    for (int ji = 0; ji < 8; ++ji) {
        int j = j0 + jg * 8 + ji;
        float bs = bias_s[jg * 8 + ji];
        float* orow = out_lp + (size_t)(b * TXT + j) * MELT;
        #pragma unroll
        for (int ti = 0; ti < 8; ++ti) {
            int t = t0 + tg * 8 + ti;
            if (t < MELT) orow[t] = acc[ji][ti] + bs;
        }
    }
}

// ---------------------------------------------------------------------------
// Kernel B: forward DP v3. 5 waves/batch, 1 j/lane, systolic skew i = t + l.
// 3-deep rotating lp prefetch (2 group-times of latency cover), seen-cached
// ring poll, guard-free steady loop (identity-step absorption replaces t<1
// guards; latch provably can't fire for i0 <= tend-23), guarded tail.
// ---------------------------------------------------------------------------
__global__ __launch_bounds__(320) void dp_kernel(
    const float* __restrict__ lp,    // (B,320,2000) = out_lp
    const int* __restrict__ tlen,
    const int* __restrict__ mlen,
    float* __restrict__ res,         // per-b result (ws), or null
    float* __restrict__ out0)        // d_out[0] fallback
{
    __shared__ float bnd[4][2056];
    __shared__ int   prog[4];

    const int b    = blockIdx.x;
    const int tid  = threadIdx.x;
    const int w    = tid >> 6;
    const int l    = tid & 63;
    const int j    = tid;
    const int tend = mlen[b] - 1;
    const int tl   = tlen[b];

    if (tid < 4) prog[tid] = 0;

    const float* lprow = lp + (size_t)(b * TXT + j) * MELT;
    float first = lp[(size_t)b * TXT * MELT];
    float A    = (j == 0) ? first * L2E : -PADM;
    float Afin = A;

    if (l == 63 && w < 4) bnd[w][0] = -PADM;
    __syncthreads();

    // 2-deep shuffle pipe prime. Lane1's first-step pt must be -PADM (its
    // left neighbor alpha_0[0]=first arrives one iteration later via ptB).
    float prime = __shfl_up(A, 1);
    float ptA = (l == 1) ? -PADM : prime;
    float ptB = prime;

    const bool is0     = (l == 0);
    const bool isPub   = (l == 63) && (w < 4);
    const bool hasRing = (w > 0);
    int seen = 0;

    const int imax = tend + 63;

    // Prefetch buffers: current(scaled) / next(raw,arrived) / loading.
    float PA[8], PB[8], PC[8];
    // Prologue: groups i0=1 -> PA, i0=9 -> PB. Unclamped: negative t reads
    // land in the previous row's tail (valid memory; values absorbed by the
    // -1e12 identity steps). j=0 (l=0) never goes negative.
    #pragma unroll
    for (int q = 0; q < 8; ++q) PA[q] = lprow[1 + q - l];
    #pragma unroll
    for (int q = 0; q < 8; ++q) PB[q] = lprow[9 + q - l];
    #pragma unroll
    for (int q = 0; q < 8; ++q) PA[q] = fmaf(PA[q], L2E, EPSL2);

    const float* pref = lprow + 17 - l;   // load cursor for group i0+16

#define RING_S(I0_)                                                          \
    float bq[8];                                                             \
    if (hasRing) {                                                           \
        const int t0_ = (I0_) - 1;                                           \
        const int need_ = t0_ + 7;                                           \
        if (seen < need_) {                                                  \
            volatile int* pv_ = &prog[w - 1];                                \
            int v_ = *pv_;                                                   \
            while (v_ < need_) { __builtin_amdgcn_s_sleep(1); v_ = *pv_; }   \
            seen = v_;                                                       \
        }                                                                    \
        float4 r0_ = *(const float4*)&bnd[w - 1][t0_];                       \
        float4 r1_ = *(const float4*)&bnd[w - 1][t0_ + 4];                   \
        bq[0]=r0_.x; bq[1]=r0_.y; bq[2]=r0_.z; bq[3]=r0_.w;                  \
        bq[4]=r1_.x; bq[5]=r1_.y; bq[6]=r1_.z; bq[7]=r1_.w;                  \
    } else {                                                                 \
        _Pragma("unroll") for (int q_=0;q_<8;++q_) bq[q_] = -PADM;           \
    }

#define GROUP_S(Pc_, Pm_, Pl_, I0_)                                          \
{                                                                            \
    RING_S(I0_)                                                              \
    _Pragma("unroll") for (int q_=0;q_<8;++q_) Pl_[q_] = pref[q_];           \
    float aq[8];                                                             \
    _Pragma("unroll")                                                        \
    for (int q_=0;q_<8;++q_) {                                               \
        float pt_ = is0 ? bq[q_] : ptA;                                      \
        float m_  = fmaxf(A, pt_);                                           \
        float d_  = A - pt_;                                                 \
        float e_  = __builtin_amdgcn_exp2f(-fabsf(d_));                      \
        float lg_ = __builtin_amdgcn_logf(1.0f + e_);                        \
        A = m_ + lg_ + Pc_[q_];                                              \
        aq[q_] = A;                                                          \
        float ns_ = __shfl_up(A, 1);                                         \
        ptA = ptB; ptB = ns_;                                                \
    }                                                                        \
    if (isPub) {                                                             \
        const int t63_ = (I0_) - 63;                                         \
        if (t63_ >= 1) {                                                     \
            _Pragma("unroll") for (int q_=0;q_<8;++q_)                       \
                bnd[w][t63_ + q_] = aq[q_];                                  \
        } else {                                                             \
            _Pragma("unroll") for (int q_=0;q_<8;++q_)                       \
                if (t63_ + q_ >= 1) bnd[w][t63_ + q_] = aq[q_];              \
        }                                                                    \
        __asm__ volatile("s_waitcnt lgkmcnt(0)" ::: "memory");               \
        int pgv_ = t63_ + 7;                                                 \
        if (pgv_ >= 1) prog[w] = pgv_;                                       \
    }                                                                        \
    pref += 8;                                                               \
    _Pragma("unroll") for (int q_=0;q_<8;++q_)                               \
        Pm_[q_] = fmaf(Pm_[q_], L2E, EPSL2);                                 \
}

#define GROUP_T(Pc_, Pm_, Pl_, I0_)                                          \
{                                                                            \
    float bq[8];                                                             \
    if (hasRing) {                                                           \
        const int t0_ = (I0_) - 1;                                           \
        int need_ = t0_ + 7; if (need_ > tend - 1) need_ = tend - 1;         \
        if (need_ >= 1 && seen < need_) {                                    \
            volatile int* pv_ = &prog[w - 1];                                \
            int v_ = *pv_;                                                   \
            while (v_ < need_) { __builtin_amdgcn_s_sleep(1); v_ = *pv_; }   \
            seen = v_;                                                       \
        }                                                                    \
        const int rb_ = t0_ > 2048 ? 2048 : t0_;                             \
        float4 r0_ = *(const float4*)&bnd[w - 1][rb_];                       \
        float4 r1_ = *(const float4*)&bnd[w - 1][rb_ + 4];                   \
        bq[0]=r0_.x; bq[1]=r0_.y; bq[2]=r0_.z; bq[3]=r0_.w;                  \
        bq[4]=r1_.x; bq[5]=r1_.y; bq[6]=r1_.z; bq[7]=r1_.w;                  \
    } else {                                                                 \
        _Pragma("unroll") for (int q_=0;q_<8;++q_) bq[q_] = -PADM;           \
    }                                                                        \
    _Pragma("unroll") for (int q_=0;q_<8;++q_) {                             \
        int t_ = (I0_) + 16 + q_ - l;                                        \
        t_ = t_ < 0 ? 0 : (t_ > tend ? tend : t_);                           \
        Pl_[q_] = lprow[t_];                                                 \
    }                                                                        \
    float aq[8];                                                             \
    const int vt_ = (I0_) - l;                                               \
    _Pragma("unroll")                                                        \
    for (int q_=0;q_<8;++q_) {                                               \
        float pt_ = is0 ? bq[q_] : ptA;                                      \
        float m_  = fmaxf(A, pt_);                                           \
        float d_  = A - pt_;                                                 \
        float e_  = __builtin_amdgcn_exp2f(-fabsf(d_));                      \
        float lg_ = __builtin_amdgcn_logf(1.0f + e_);                        \
        A = m_ + lg_ + Pc_[q_];                                              \
        aq[q_] = A;                                                          \
        Afin = (vt_ + q_ == tend) ? A : Afin;                                \
        float ns_ = __shfl_up(A, 1);                                         \
        ptA = ptB; ptB = ns_;                                                \
    }                                                                        \
    if (isPub) {                                                             \
        const int t63_ = (I0_) - 63;                                         \
        _Pragma("unroll") for (int q_=0;q_<8;++q_) {                         \
            int tq_ = t63_ + q_;                                             \
            if (tq_ >= 1 && tq_ <= tend) bnd[w][tq_] = aq[q_];               \
        }                                                                    \
        __asm__ volatile("s_waitcnt lgkmcnt(0)" ::: "memory");               \
        int pgv_ = t63_ + 7; if (pgv_ > tend) pgv_ = tend;                   \
        if (pgv_ >= 1) prog[w] = pgv_;                                       \
    }                                                                        \
    _Pragma("unroll") for (int q_=0;q_<8;++q_)                               \
        Pm_[q_] = fmaf(Pm_[q_], L2E, EPSL2);                                 \
}

    int i0 = 1;
    const int sEnd = tend - 23;   // steady: loads in-bounds, latch can't fire
    int ph = 0;
    while (i0 <= sEnd) {
        GROUP_S(PA, PB, PC, i0); i0 += 8;
        if (i0 > sEnd) { ph = 1; break; }
        GROUP_S(PB, PC, PA, i0); i0 += 8;
        if (i0 > sEnd) { ph = 2; break; }
        GROUP_S(PC, PA, PB, i0); i0 += 8;
    }
    // canonicalize rotation so PA = current
    if (ph == 1) {
        #pragma unroll
        for (int q = 0; q < 8; ++q) {
            float tmp = PA[q]; PA[q] = PB[q]; PB[q] = PC[q]; PC[q] = tmp;
        }
    } else if (ph == 2) {
        #pragma unroll
        for (int q = 0; q < 8; ++q) {
            float tmp = PA[q]; PA[q] = PC[q]; PC[q] = PB[q]; PB[q] = tmp;
        }
    }
    while (i0 <= imax) {
        GROUP_T(PA, PB, PC, i0); i0 += 8;
        if (i0 > imax) break;
        GROUP_T(PB, PC, PA, i0); i0 += 8;
        if (i0 > imax) break;
        GROUP_T(PC, PA, PB, i0); i0 += 8;
    }

#undef GROUP_S
#undef GROUP_T
#undef RING_S

    if (j == tl - 1) {
        float v = Afin * LN2 / (float)(tend + 1);
        if (res) res[b] = v;
        else     atomicAdd(out0, -v / (float)BATCH);
    }
}

__global__ void zero1_kernel(float* out0) { out0[0] = 0.f; }

__global__ void fin_kernel(const float* __restrict__ res, float* __restrict__ out0)
{
    int l = threadIdx.x;
    float v = (l < BATCH) ? res[l] : 0.f;
    #pragma unroll
    for (int off = 32; off; off >>= 1) v += __shfl_down(v, off);
    if (l == 0) out0[0] = -(v / (float)BATCH);
}

// ---------------------------------------------------------------------------
extern "C" void kernel_launch(void* const* d_in, const int* in_sizes, int n_in,
                              void* d_out, int out_size, void* d_ws, size_t ws_size,
                              hipStream_t stream)
{
    const float* mlv = (const float*)d_in[0];
    const float* ms  = (const float*)d_in[1];
    const int*   tl  = (const int*)d_in[2];
    const int*   ml  = (const int*)d_in[3];
    float* out    = (float*)d_out;
    float* out_lp = out + 1;

    bool res_ok = ws_size >= 64;
    float* res = res_ok ? (float*)d_ws : nullptr;

    dim3 gA(8, 5, 16);   // t-tiles(256), j-tiles(64), batch
    lp_kernel<<<gA, 256, 0, stream>>>(mlv, ms, out_lp);

    if (!res_ok) zero1_kernel<<<1, 1, 0, stream>>>(out);
    dp_kernel<<<BATCH, 320, 0, stream>>>(out_lp, tl, ml, res, out);
    if (res_ok) fin_kernel<<<1, 64, 0, stream>>>(res, out);
}